// Round 3
// baseline (410.608 us; speedup 1.0000x reference)
//
#include <hip/hip_runtime.h>
#include <math.h>

// Problem constants (match reference.py)
#define HS_D       1024   // input_size
#define HS_MAXLEN  24     // max Huffman path depth
#define HS_MAXPAIR 12     // max step-pairs per example

// One WAVE per example, DEFERRED reduction.
//   - x fragment loaded ONCE into regs (16 floats/lane) -> x traffic
//     221 MB -> 32 MB vs the per-pair-wave version
//   - pair loop is pure load+FMA into 24 persistent per-lane partials:
//     no cross-lane ops, no softplus inside the loop, accumulators are
//     independent across pairs so W loads pipeline (this is what round-1's
//     per-example attempt got wrong: a ~750-cycle dependent
//     shuffle+softplus chain per pair)
//   - ONE guarded butterfly-reduce + softplus tail at wave end
//   - lane 0 plain-stores ws[n]: no atomics, no memset, no worklist
// All guards test wave-uniform npair/L -> s_cbranch, zero divergence.
__global__ __launch_bounds__(256) void hsm_ex_kernel(
    const float* __restrict__ x,      // [N_EX, D]
    const float* __restrict__ W,      // [N_DEC, D]
    const int*   __restrict__ t,      // [N_EX]
    const int*   __restrict__ paths,  // [V, MAX_LEN]
    const float* __restrict__ codes,  // [V, MAX_LEN]
    const int*   __restrict__ lens,   // [V]
    float*       __restrict__ ws,     // [>= n_ex] floats (poison ok)
    int n_ex)
{
    const int tid  = threadIdx.x;
    const int lane = tid & 63;
    const int n    = blockIdx.x * 4 + (tid >> 6);
    if (n >= n_ex) return;

    const int leaf  = __builtin_amdgcn_readfirstlane(t[n]);
    const int L     = __builtin_amdgcn_readfirstlane(lens[leaf]);
    const int npair = (L + 1) >> 1;

    // x fragment: 16 floats/lane; each float4 load is a contiguous 1 KB
    // wave-level segment.
    const float4* x4 = (const float4*)(x + (size_t)n * HS_D);
    float4 xf[4];
#pragma unroll
    for (int j = 0; j < 4; ++j) xf[j] = x4[j * 64 + lane];

    const int*   prow = paths + leaf * HS_MAXLEN;
    const float* crow = codes + leaf * HS_MAXLEN;

    // Phase A: gather node ids for all valid pairs. readfirstlane pins
    // them to SGPRs (24 SGPRs, cheap); loads issue back-to-back.
    int nd0[HS_MAXPAIR], nd1[HS_MAXPAIR];
#pragma unroll
    for (int p = 0; p < HS_MAXPAIR; ++p) {
        if (p < npair) {                              // wave-uniform
            const int  l0 = 2 * p, l1 = l0 + 1;
            const bool v1 = (l1 < L);                 // wave-uniform
            nd0[p] = __builtin_amdgcn_readfirstlane(prow[l0]);
            // clamp invalid second step to node0: duplicate address -> L1 hit
            nd1[p] = __builtin_amdgcn_readfirstlane(v1 ? prow[l1] : prow[l0]);
        }
    }

    // Phase B: stream W rows, accumulate per-lane partial dots. d[] is
    // statically indexed everywhere (rule: runtime-indexed arrays spill
    // to scratch).
    float d[2 * HS_MAXPAIR];
#pragma unroll
    for (int k = 0; k < 2 * HS_MAXPAIR; ++k) d[k] = 0.0f;

#pragma unroll
    for (int p = 0; p < HS_MAXPAIR; ++p) {
        if (p < npair) {                              // wave-uniform
            const float4* w0 = (const float4*)(W + (size_t)nd0[p] * HS_D);
            const float4* w1 = (const float4*)(W + (size_t)nd1[p] * HS_D);
            float4 wf0[4], wf1[4];
#pragma unroll
            for (int j = 0; j < 4; ++j) wf0[j] = w0[j * 64 + lane];
#pragma unroll
            for (int j = 0; j < 4; ++j) wf1[j] = w1[j * 64 + lane];

            float s0 = 0.0f, s1 = 0.0f;
#pragma unroll
            for (int j = 0; j < 4; ++j) {
                s0 += xf[j].x * wf0[j].x + xf[j].y * wf0[j].y
                    + xf[j].z * wf0[j].z + xf[j].w * wf0[j].w;
                s1 += xf[j].x * wf1[j].x + xf[j].y * wf1[j].y
                    + xf[j].z * wf1[j].z + xf[j].w * wf1[j].w;
            }
            d[2 * p]     = s0;
            d[2 * p + 1] = s1;
        }
    }

    // Phase C: one cross-lane reduction pass for all valid pairs.
    // 6-round xor butterfly per value; chains are independent (6-deep
    // each), so they pipeline — unlike round-1's per-pair serial chain.
#pragma unroll
    for (int p = 0; p < HS_MAXPAIR; ++p) {
        if (p < npair) {
#pragma unroll
            for (int off = 32; off > 0; off >>= 1) {
                d[2 * p]     += __shfl_xor(d[2 * p],     off);
                d[2 * p + 1] += __shfl_xor(d[2 * p + 1], off);
            }
        }
    }

    // Phase D: softplus + accumulate. All lanes redundantly compute the
    // same scalars (butterfly broadcast) -> no divergence; lane 0 stores.
    float vsum = 0.0f;
#pragma unroll
    for (int p = 0; p < HS_MAXPAIR; ++p) {
        if (p < npair) {
            const int l0 = 2 * p, l1 = l0 + 1;
            const float z0 = -crow[l0] * d[2 * p];
            vsum += fmaxf(z0, 0.0f) + log1pf(expf(-fabsf(z0)));
            if (l1 < L) {                             // wave-uniform
                const float z1 = -crow[l1] * d[2 * p + 1];
                vsum += fmaxf(z1, 0.0f) + log1pf(expf(-fabsf(z1)));
            }
        }
    }

    if (lane == 0) ws[n] = vsum;   // plain store: slot owned by this wave
}

// One-block finish: sum ws[0..n_ex) -> out[0]. 256 threads, float4 loads,
// wave butterfly + tiny LDS cross-wave combine. Reads ONLY written slots,
// so no zero-init of ws is needed.
__global__ __launch_bounds__(256) void hsm_finish_kernel(
    const float* __restrict__ ws, float* __restrict__ out, int n_ex)
{
    __shared__ float part[4];
    const int tid = threadIdx.x;

    float s = 0.0f;
    const int n4 = n_ex >> 2;                       // float4 count
    const float4* w4 = (const float4*)ws;
    for (int k = tid; k < n4; k += 256) {
        const float4 v = w4[k];
        s += v.x + v.y + v.z + v.w;
    }
    if (tid < (n_ex & 3)) s += ws[(n_ex & ~3) + tid];   // scalar tail

#pragma unroll
    for (int off = 32; off > 0; off >>= 1)
        s += __shfl_xor(s, off);

    if ((tid & 63) == 0) part[tid >> 6] = s;
    __syncthreads();
    if (tid == 0) out[0] = part[0] + part[1] + part[2] + part[3];
}

extern "C" void kernel_launch(void* const* d_in, const int* in_sizes, int n_in,
                              void* d_out, int out_size, void* d_ws, size_t ws_size,
                              hipStream_t stream) {
    const float* x     = (const float*)d_in[0];
    const float* W     = (const float*)d_in[1];
    const int*   t     = (const int*)  d_in[2];
    const int*   paths = (const int*)  d_in[3];
    const float* codes = (const float*)d_in[4];
    const int*   lens  = (const int*)  d_in[5];
    float* out = (float*)d_out;
    float* ws  = (float*)d_ws;

    const int n_ex = in_sizes[2];  // t has N_EX elements

    // One wave per example; 4 waves per 256-thread block.
    // Two dispatches total: no memset, no build kernel, no atomics.
    const int n_blocks = (n_ex + 3) / 4;
    hsm_ex_kernel<<<n_blocks, 256, 0, stream>>>(x, W, t, paths, codes, lens,
                                                ws, n_ex);
    hsm_finish_kernel<<<1, 256, 0, stream>>>(ws, out, n_ex);
}

// Round 5
// 384.080 us; speedup vs baseline: 1.0691x; 1.0691x over previous
//
#include <hip/hip_runtime.h>
#include <math.h>

// Problem constants (match reference.py)
#define HS_D       1024   // input_size
#define HS_MAXLEN  24     // max Huffman path depth

#define RFL(v) __builtin_amdgcn_readfirstlane(v)

__device__ __forceinline__ float softplus_of(float c, float d) {
    // softplus(-c*d), stable form
    const float z = -c * d;
    return fmaxf(z, 0.0f) + log1pf(expf(-fabsf(z)));
}

// One WAVE per (example, slot-group). Wave w of block n handles pair slots
// {w, w+4, w+8} of example n (pairs = consecutive step duos). Properties:
//   - max 3 iterations/wave (round-3 had 12 -> tail imbalance killed it)
//   - slot 0 always live -> dead-wave fraction ~12% (round-0: 46%)
//   - x fragment loaded ONCE per wave; block's 4 waves share the row in L1
//   - explicit 2-deep W pipeline: slot-1 loads issue before slot-0
//     consumes; slot-2 reuses slot-0's registers -> two 8KB batches in
//     flight per wave (round 0/3 drained vmcnt between pairs)
//   - __launch_bounds__(256,4): <=128 VGPR -> 16 waves/CU (round 3: 132
//     VGPR, eff. ~2.4 waves/CU)
//   - lane 0 plain-stores ws[4n+w]; dead waves store 0 -> no atomics, no
//     memset; finish sums exactly [0, 4*n_ex)
// All guards test wave-uniform npair/L -> s_cbranch, zero divergence.
__global__ __launch_bounds__(256, 4) void hsm_slot_kernel(
    const float* __restrict__ x,      // [N_EX, D]
    const float* __restrict__ W,      // [N_DEC, D]
    const int*   __restrict__ t,      // [N_EX]
    const int*   __restrict__ paths,  // [V, MAX_LEN]
    const float* __restrict__ codes,  // [V, MAX_LEN]
    const int*   __restrict__ lens,   // [V]
    float*       __restrict__ ws)     // [4 * N_EX] floats (poison ok)
{
    const int tid  = threadIdx.x;
    const int lane = tid & 63;
    const int n    = blockIdx.x;          // example
    const int w    = tid >> 6;            // slot-group 0..3
    const int gw   = n * 4 + w;

    const int leaf  = RFL(t[n]);
    const int L     = RFL(lens[leaf]);
    const int npair = (L + 1) >> 1;       // 1..12

    if (w >= npair) {                     // wave-uniform dead exit
        if (lane == 0) ws[gw] = 0.0f;
        return;
    }

    const int*   prow = paths + leaf * HS_MAXLEN;
    const float* crow = codes + leaf * HS_MAXLEN;

    const bool a1 = (w + 4) < npair;      // slot-1 live (wave-uniform)
    const bool a2 = (w + 8) < npair;      // slot-2 live

    // Step indices per slot (l < 24 always, so unguarded reads are safe).
    const int l00 = 2 * w,        l01 = l00 + 1;
    const int l10 = 2 * (w + 4),  l11 = l10 + 1;
    const int l20 = 2 * (w + 8),  l21 = l20 + 1;
    const bool v01 = l01 < L, v11 = l11 < L, v21 = l21 < L;

    // Scalar node ids; invalid second step clamps to first (L1 dup hit).
    const int nd00 = RFL(prow[l00]);
    const int nd01 = RFL(v01 ? prow[l01] : prow[l00]);

    // x fragment: 16 floats/lane, 4 contiguous 1 KB wave segments.
    const float4* x4 = (const float4*)(x + (size_t)n * HS_D);
    float4 xf[4];
#pragma unroll
    for (int j = 0; j < 4; ++j) xf[j] = x4[j * 64 + lane];

    // ---- pipeline stage A: issue slot-0 W loads ----
    const float4* wA0 = (const float4*)(W + (size_t)nd00 * HS_D);
    const float4* wA1 = (const float4*)(W + (size_t)nd01 * HS_D);
    float4 fA0[4], fA1[4];
#pragma unroll
    for (int j = 0; j < 4; ++j) fA0[j] = wA0[j * 64 + lane];
#pragma unroll
    for (int j = 0; j < 4; ++j) fA1[j] = wA1[j * 64 + lane];

    // ---- pipeline stage B: issue slot-1 W loads before consuming A ----
    float4 fB0[4], fB1[4];
    if (a1) {
        const int nd10 = RFL(prow[l10]);
        const int nd11 = RFL(v11 ? prow[l11] : prow[l10]);
        const float4* wB0 = (const float4*)(W + (size_t)nd10 * HS_D);
        const float4* wB1 = (const float4*)(W + (size_t)nd11 * HS_D);
#pragma unroll
        for (int j = 0; j < 4; ++j) fB0[j] = wB0[j * 64 + lane];
#pragma unroll
        for (int j = 0; j < 4; ++j) fB1[j] = wB1[j * 64 + lane];
    }

    // ---- consume A (slot 0) ----
    float d00 = 0.0f, d01 = 0.0f;
#pragma unroll
    for (int j = 0; j < 4; ++j) {
        d00 += xf[j].x * fA0[j].x + xf[j].y * fA0[j].y
             + xf[j].z * fA0[j].z + xf[j].w * fA0[j].w;
        d01 += xf[j].x * fA1[j].x + xf[j].y * fA1[j].y
             + xf[j].z * fA1[j].z + xf[j].w * fA1[j].w;
    }

    // ---- issue slot-2 W loads into A's registers (2-deep steady state) ----
    if (a2) {
        const int nd20 = RFL(prow[l20]);
        const int nd21 = RFL(v21 ? prow[l21] : prow[l20]);
        const float4* wC0 = (const float4*)(W + (size_t)nd20 * HS_D);
        const float4* wC1 = (const float4*)(W + (size_t)nd21 * HS_D);
#pragma unroll
        for (int j = 0; j < 4; ++j) fA0[j] = wC0[j * 64 + lane];
#pragma unroll
        for (int j = 0; j < 4; ++j) fA1[j] = wC1[j * 64 + lane];
    }

    // ---- consume B (slot 1) ----
    float d10 = 0.0f, d11 = 0.0f;
    if (a1) {
#pragma unroll
        for (int j = 0; j < 4; ++j) {
            d10 += xf[j].x * fB0[j].x + xf[j].y * fB0[j].y
                 + xf[j].z * fB0[j].z + xf[j].w * fB0[j].w;
            d11 += xf[j].x * fB1[j].x + xf[j].y * fB1[j].y
                 + xf[j].z * fB1[j].z + xf[j].w * fB1[j].w;
        }
    }

    // ---- consume A again (slot 2) ----
    float d20 = 0.0f, d21 = 0.0f;
    if (a2) {
#pragma unroll
        for (int j = 0; j < 4; ++j) {
            d20 += xf[j].x * fA0[j].x + xf[j].y * fA0[j].y
                 + xf[j].z * fA0[j].z + xf[j].w * fA0[j].w;
            d21 += xf[j].x * fA1[j].x + xf[j].y * fA1[j].y
                 + xf[j].z * fA1[j].z + xf[j].w * fA1[j].w;
        }
    }

    // ---- one interleaved butterfly pass for all live values ----
#pragma unroll
    for (int off = 32; off > 0; off >>= 1) {
        d00 += __shfl_xor(d00, off);
        d01 += __shfl_xor(d01, off);
        if (a1) { d10 += __shfl_xor(d10, off); d11 += __shfl_xor(d11, off); }
        if (a2) { d20 += __shfl_xor(d20, off); d21 += __shfl_xor(d21, off); }
    }

    // ---- softplus tail (all lanes redundantly; broadcast values) ----
    float vsum = softplus_of(crow[l00], d00);
    if (v01) vsum += softplus_of(crow[l01], d01);
    if (a1) {
        vsum += softplus_of(crow[l10], d10);
        if (v11) vsum += softplus_of(crow[l11], d11);
    }
    if (a2) {
        vsum += softplus_of(crow[l20], d20);
        if (v21) vsum += softplus_of(crow[l21], d21);
    }

    if (lane == 0) ws[gw] = vsum;   // plain store: slot owned by this wave
}

// One-block finish: sum ws[0..cnt) -> out[0]. Reads ONLY written slots,
// so no zero-init of ws is needed.
__global__ __launch_bounds__(256) void hsm_finish_kernel(
    const float* __restrict__ ws, float* __restrict__ out, int cnt)
{
    __shared__ float part[4];
    const int tid = threadIdx.x;

    float s = 0.0f;
    const int n4 = cnt >> 2;                        // float4 count
    const float4* w4 = (const float4*)ws;
    for (int k = tid; k < n4; k += 256) {
        const float4 v = w4[k];
        s += v.x + v.y + v.z + v.w;
    }
    if (tid < (cnt & 3)) s += ws[(cnt & ~3) + tid]; // scalar tail

#pragma unroll
    for (int off = 32; off > 0; off >>= 1)
        s += __shfl_xor(s, off);

    if ((tid & 63) == 0) part[tid >> 6] = s;
    __syncthreads();
    if (tid == 0) out[0] = part[0] + part[1] + part[2] + part[3];
}

extern "C" void kernel_launch(void* const* d_in, const int* in_sizes, int n_in,
                              void* d_out, int out_size, void* d_ws, size_t ws_size,
                              hipStream_t stream) {
    const float* x     = (const float*)d_in[0];
    const float* W     = (const float*)d_in[1];
    const int*   t     = (const int*)  d_in[2];
    const int*   paths = (const int*)  d_in[3];
    const float* codes = (const float*)d_in[4];
    const int*   lens  = (const int*)  d_in[5];
    float* out = (float*)d_out;
    float* ws  = (float*)d_ws;

    const int n_ex = in_sizes[2];  // t has N_EX elements

    // One block per example, 4 slot-group waves per block.
    // Two dispatches total: no memset, no atomics.
    hsm_slot_kernel<<<n_ex, 256, 0, stream>>>(x, W, t, paths, codes, lens, ws);
    hsm_finish_kernel<<<1, 256, 0, stream>>>(ws, out, 4 * n_ex);
}

// Round 6
// 326.992 us; speedup vs baseline: 1.2557x; 1.1746x over previous
//
#include <hip/hip_runtime.h>
#include <math.h>

// Problem constants (match reference.py)
#define HS_D       1024   // input_size
#define HS_MAXLEN  24     // max Huffman path depth
#define HS_PAIRS   12     // step-pairs per example (24/2)
#define HS_NBUCKET 512    // partial-sum buckets in d_ws

// One WAVE per (example, step-pair) — the measured-best structure (round 0,
// 324.2 us total; every amortization attempt measured worse):
//   - single-shot waves, maximal concurrency (~98k waves) is what keeps the
//     random 4 KB W-row gather at ~5 TB/s effective (floor ~63 us for the
//     253 MB fetch + 143 MB poison-writeback measured in round 5)
//   - loads its 16-float fragment of x[n]          (4 x float4, coalesced)
//   - loads 16-float fragments of W[node0],W[node1](8 x float4, coalesced)
//   - two dot products, interleaved butterfly reduce, masked softplus
//   - lane 0 atomicAdd into a staggered bucket in ws
// 512-thread blocks (8 waves): the 12 pairs of an example span ~1.5 blocks,
// so co-resident waves hit the same x row in L1 (round 0 used 4-wave blocks).
// Invalid trailing step clamps its node to node0 (duplicate address -> L1
// hit, no HBM waste). Waves fully past the path length exit immediately
// (wave-uniform branch).
__global__ __launch_bounds__(512) void hsm_pair_kernel(
    const float* __restrict__ x,      // [N_EX, D]
    const float* __restrict__ W,      // [N_DEC, D]
    const int*   __restrict__ t,      // [N_EX]
    const int*   __restrict__ paths,  // [V, MAX_LEN]
    const float* __restrict__ codes,  // [V, MAX_LEN]
    const int*   __restrict__ lens,   // [V]
    float*       __restrict__ ws,     // [HS_NBUCKET] zero-initialized
    int n_ex)
{
    const int tid  = threadIdx.x;
    const int lane = tid & 63;
    const int gw   = blockIdx.x * 8 + (tid >> 6);  // global wave id
    const int n    = gw / HS_PAIRS;                // example
    const int p    = gw % HS_PAIRS;                // step-pair

    const int leaf = t[n];                 // wave-uniform -> scalar load
    const int L    = lens[leaf];           // wave-uniform
    const int l0   = 2 * p;
    const int l1   = l0 + 1;
    if (l0 >= L) return;                   // wave-uniform early exit

    const int   node0 = paths[leaf * HS_MAXLEN + l0];
    const float c0    = codes[leaf * HS_MAXLEN + l0];
    const bool  v1    = (l1 < L);
    // Clamp invalid second step to node0: duplicate address -> L1 hit.
    const int   node1 = v1 ? paths[leaf * HS_MAXLEN + l1] : node0;
    const float c1    = v1 ? codes[leaf * HS_MAXLEN + l1] : 1.0f;

    const float4* x4 = (const float4*)(x + (size_t)n     * HS_D);
    const float4* w0 = (const float4*)(W + (size_t)node0 * HS_D);
    const float4* w1 = (const float4*)(W + (size_t)node1 * HS_D);

    // Issue all 12 loads before consuming (12 float4 = 48 VGPRs: fits).
    float4 xf[4], wf0[4], wf1[4];
#pragma unroll
    for (int j = 0; j < 4; ++j) xf[j]  = x4[j * 64 + lane];
#pragma unroll
    for (int j = 0; j < 4; ++j) wf0[j] = w0[j * 64 + lane];
#pragma unroll
    for (int j = 0; j < 4; ++j) wf1[j] = w1[j * 64 + lane];

    float d0 = 0.0f, d1 = 0.0f;
#pragma unroll
    for (int j = 0; j < 4; ++j) {
        d0 += xf[j].x * wf0[j].x + xf[j].y * wf0[j].y
            + xf[j].z * wf0[j].z + xf[j].w * wf0[j].w;
        d1 += xf[j].x * wf1[j].x + xf[j].y * wf1[j].y
            + xf[j].z * wf1[j].z + xf[j].w * wf1[j].w;
    }

    // Two interleaved 64-lane butterfly reductions.
#pragma unroll
    for (int off = 32; off > 0; off >>= 1) {
        d0 += __shfl_down(d0, off);
        d1 += __shfl_down(d1, off);
    }

    if (lane == 0) {
        const float z0 = -c0 * d0;
        float v = fmaxf(z0, 0.0f) + log1pf(expf(-fabsf(z0)));
        if (v1) {
            const float z1 = -c1 * d1;
            v += fmaxf(z1, 0.0f) + log1pf(expf(-fabsf(z1)));
        }
        atomicAdd(&ws[gw & (HS_NBUCKET - 1)], v);
    }
}

// Single-wave finish: sum the buckets, write the scalar output.
__global__ __launch_bounds__(64) void hsm_finish_kernel(
    const float* __restrict__ ws, float* __restrict__ out)
{
    const int lane = threadIdx.x;
    float s = 0.0f;
#pragma unroll
    for (int k = 0; k < HS_NBUCKET / 64; ++k)
        s += ws[lane + 64 * k];
#pragma unroll
    for (int off = 32; off > 0; off >>= 1)
        s += __shfl_down(s, off);
    if (lane == 0) out[0] = s;
}

extern "C" void kernel_launch(void* const* d_in, const int* in_sizes, int n_in,
                              void* d_out, int out_size, void* d_ws, size_t ws_size,
                              hipStream_t stream) {
    const float* x     = (const float*)d_in[0];
    const float* W     = (const float*)d_in[1];
    const int*   t     = (const int*)  d_in[2];
    const int*   paths = (const int*)  d_in[3];
    const float* codes = (const float*)d_in[4];
    const int*   lens  = (const int*)  d_in[5];
    float* out = (float*)d_out;
    float* ws  = (float*)d_ws;

    const int n_ex = in_sizes[2];  // t has N_EX elements

    // ws is re-poisoned 0xAA before every timed launch -> zero the buckets.
    hipMemsetAsync(ws, 0, HS_NBUCKET * sizeof(float), stream);

    const int n_waves  = n_ex * HS_PAIRS;
    const int n_blocks = (n_waves + 7) / 8;   // 8 waves per 512-thr block
    hsm_pair_kernel<<<n_blocks, 512, 0, stream>>>(x, W, t, paths, codes, lens,
                                                  ws, n_ex);
    hsm_finish_kernel<<<1, 64, 0, stream>>>(ws, out);
}